// Round 4
// baseline (188.169 us; speedup 1.0000x reference)
//
#include <hip/hip_runtime.h>
#include <stdint.h>

// MeshConvPoint: B=8, C=64, V=25000, D=12, O=64
// out[b,o,v] = bias[o] + sum_c W0[o,c]*x[b,c,v] + (1/deg)*sum_{d<deg} y1[b,o,nbr[b,v,d]]
//
// R11: gather back to pure streaming + persistent pipeline. R10 counters:
// gather_out 46us at 1.2% MFMA / 23% VALU / 26% HBM / 57% occ -- latency-
// bound serial chain per tile (idx -> MFMA-self -> 12 gathers -> barrier
// drain -> accum -> barrier -> store). Changes:
//   ygemm3: both planes from one LDS tile (16 MFMA/wave, acc=32 AGPR),
//           y0 = plane0+bias (bf16, nt), y1 = plane1. xt plane deleted.
//   gather3: persistent 2048 blocks (256/batch, XCD-pinned), grid-stride
//           ~3 tiles each, 2-deep prefetch (next tile's idx/deg/y0 issued
//           under current tile's y1 latency), double-buffered LDS, ONE
//           barrier/tile, zero MFMA.
// XCD pin everywhere: blockIdx.x&7 = b (producer/consumer L2 affinity).

#define NB 8
#define NC 64
#define NV 25000
#define ND 12
#define NO 64
#define VROW 32        // y0/y1 row stride in dwords (64 bf16 = 128 B)
#define ATL 391        // ceil(25000/64) tiles for ygemm3 (64 v / block)
#define NTB 782        // ceil(25000/32) 32-v tiles per batch for gather
#define GTB 256        // gather blocks per batch (persistent)

typedef uint32_t u32x4 __attribute__((ext_vector_type(4)));
typedef uint32_t u32x2 __attribute__((ext_vector_type(2)));
typedef __bf16  bf16x8 __attribute__((ext_vector_type(8)));
typedef float   f32x4  __attribute__((ext_vector_type(4)));

__device__ inline uint32_t bf16pack(float a, float b) {
    uint32_t ua = __float_as_uint(a), ub = __float_as_uint(b);
    ua = (ua + 0x7fffu + ((ua >> 16) & 1u)) >> 16;
    ub = (ub + 0x7fffu + ((ub >> 16) & 1u)) >> 16;
    return ua | (ub << 16);
}
__device__ inline float blo(uint32_t u) { return __uint_as_float(u << 16); }
__device__ inline float bhi(uint32_t u) { return __uint_as_float(u & 0xffff0000u); }

// ---- K0: W[o][c][k] -> Wcb[m][c-pair] bf16, m = k*64 + o ----
__global__ __launch_bounds__(256) void wt_kernel(const float* __restrict__ W,
                                                 uint32_t* __restrict__ Wcb) {
    int i = blockIdx.x * 256 + threadIdx.x;  // i in [0, 4096)
    int m = i >> 5;             // 0..127
    int c = (i & 31) * 2;       // 0..62 even
    int k = m >> 6;             // plane
    int o = m & 63;
    float s0 = W[o * (NC * 2) + c * 2 + k];
    float s1 = W[o * (NC * 2) + (c + 1) * 2 + k];
    Wcb[i] = bf16pack(s0, s1);
}

// ---- K1: x[b][c][v] -> y0 (plane0+bias) and y1 (plane1), bf16 rows ----
// 64 v / block. Stage: lane=v, wave covers 16 channels, 8 packs buffered ->
// 2x ds_write_b128 (low conflict). Rows [v][c-pair] stride 36 dw (144 B,
// 16B-aligned). Wave w: v-sub w*16..+16, 2 kt x 2 plane x 4 mt = 16 MFMAs,
// acc[2][4] = 32 AGPR (~75 regs total -> ~6 waves/SIMD).
__global__ __launch_bounds__(256) void ygemm3(const float* __restrict__ x,
                                              const uint32_t* __restrict__ Wcb,
                                              const float* __restrict__ bias,
                                              uint32_t* __restrict__ y0,
                                              uint32_t* __restrict__ y1) {
    __shared__ uint32_t lb[64 * 36];
    const int b = blockIdx.x & 7;      // XCD pin
    const int tile = blockIdx.x >> 3;
    const int vbase = tile * 64;
    const int lane = threadIdx.x & 63, wave = threadIdx.x >> 6;
    const float* xb = x + (size_t)b * NC * NV;

    {
        int vg = vbase + lane;
        if (vg >= NV) vg = NV - 1;
        uint32_t wb[8];
#pragma unroll
        for (int rr = 0; rr < 8; ++rr) {
            const int c = wave * 16 + rr * 2;
            float s0 = __builtin_nontemporal_load(xb + (size_t)c * NV + vg);
            float s1 = __builtin_nontemporal_load(xb + (size_t)(c + 1) * NV + vg);
            wb[rr] = bf16pack(s0, s1);
        }
        uint32_t* dst = &lb[lane * 36 + wave * 8];
        *reinterpret_cast<u32x4*>(dst)     = (u32x4){wb[0], wb[1], wb[2], wb[3]};
        *reinterpret_cast<u32x4*>(dst + 4) = (u32x4){wb[4], wb[5], wb[6], wb[7]};
    }
    __syncthreads();

    const int l15 = lane & 15, lq = lane >> 4;
    union BF { u32x4 q; bf16x8 v; } bfr[2];
#pragma unroll
    for (int kt = 0; kt < 2; ++kt)
        bfr[kt].q = *reinterpret_cast<const u32x4*>(
            &lb[(wave * 16 + l15) * 36 + kt * 16 + lq * 4]);

    f32x4 acc[2][4];
#pragma unroll
    for (int p = 0; p < 2; ++p)
#pragma unroll
        for (int mt = 0; mt < 4; ++mt) acc[p][mt] = (f32x4){0.f, 0.f, 0.f, 0.f};

#pragma unroll
    for (int kt = 0; kt < 2; ++kt) {
#pragma unroll
        for (int p = 0; p < 2; ++p) {
#pragma unroll
            for (int mt = 0; mt < 4; ++mt) {
                union { u32x4 q; bf16x8 v; } au;
                au.q = *(const u32x4*)(Wcb + (size_t)(p * 64 + mt * 16 + l15) * 32
                                           + kt * 16 + lq * 4);
                acc[p][mt] = __builtin_amdgcn_mfma_f32_16x16x32_bf16(au.v, bfr[kt].v,
                                                                     acc[p][mt], 0, 0, 0);
            }
        }
    }

    // lane holds D[o = mt*16 + lq*4 + r][v = l15]; y rows are [v][o-pair]
    const int v = vbase + wave * 16 + l15;
    if (v < NV) {
        uint32_t* yr0 = y0 + ((size_t)b * NV + v) * VROW;
        uint32_t* yr1 = y1 + ((size_t)b * NV + v) * VROW;
#pragma unroll
        for (int mt = 0; mt < 4; ++mt) {
            f32x4 a0 = acc[0][mt];
            const float* bp = bias + mt * 16 + lq * 4;
            a0[0] += bp[0]; a0[1] += bp[1]; a0[2] += bp[2]; a0[3] += bp[3];
            u32x2 p0 = {bf16pack(a0[0], a0[1]), bf16pack(a0[2], a0[3])};
            __builtin_nontemporal_store(p0, (u32x2*)(yr0 + mt * 8 + lq * 2));
            f32x4 a1 = acc[1][mt];
            u32x2 p1 = {bf16pack(a1[0], a1[1]), bf16pack(a1[2], a1[3])};
            *(u32x2*)(yr1 + mt * 8 + lq * 2) = p1;   // hot gather target: keep in L2
        }
    }
}

// ---- K2: persistent pipelined gather: out = y0 + inv * sum(y1[nbr]) ----
// 2048 blocks = 256 per batch (XCD-pinned). Each block strides over ~3
// 32-v tiles. Per tile: issue 12 y1 row-gathers, prefetch next tile's
// idx/deg/y0 under their latency, accumulate, LDS transpose (dbuf), one
// barrier, coalesced nt store. 8 lanes/vertex, 16B row chunk each.
__global__ __launch_bounds__(256) void gather3(const int* __restrict__ nbr,
                                               const int* __restrict__ deg,
                                               const uint32_t* __restrict__ y0,
                                               const uint32_t* __restrict__ y1,
                                               float* __restrict__ out) {
    __shared__ float lds[2][32 * 68];  // [buf][vloc][o], stride 68

    const int b = blockIdx.x & 7;      // XCD pin (matches producer)
    const int t0 = blockIdx.x >> 3;    // 0..255
    const int lane = threadIdx.x & 63;
    const int wave = threadIdx.x >> 6;
    const int s8 = lane >> 3;
    const int j = lane & 7;
    const int vloc = wave * 8 + s8;    // 0..31

    const int* nbrb = nbr + (size_t)b * NV * ND;
    const int* degb = deg + (size_t)b * NV;
    const uint32_t* y0b = y0 + (size_t)b * NV * VROW;
    const uint32_t* y1b = y1 + (size_t)b * NV * VROW;
    float* outb = out + (size_t)b * NO * NV;

    // prologue: prefetch tile t0's idx/deg/y0
    int idx[ND];
    int dg;
    u32x4 su;
    {
        int v = t0 * 32 + vloc;
        const int vc = v < NV ? v : NV - 1;
        const int4* p = reinterpret_cast<const int4*>(nbrb + (size_t)vc * ND);
        int4 a0 = p[0], a1 = p[1], a2 = p[2];
        idx[0] = a0.x; idx[1] = a0.y; idx[2]  = a0.z; idx[3]  = a0.w;
        idx[4] = a1.x; idx[5] = a1.y; idx[6]  = a1.z; idx[7]  = a1.w;
        idx[8] = a2.x; idx[9] = a2.y; idx[10] = a2.z; idx[11] = a2.w;
        dg = degb[vc];
        su = *(reinterpret_cast<const u32x4*>(y0b + (size_t)vc * VROW) + j);
    }

    int buf = 0;
    for (int t = t0; t < NTB; t += GTB) {
        // issue this tile's 12 masked row gathers (long latency, 12 deep)
        u32x4 rows[ND];
#pragma unroll
        for (int d = 0; d < ND; ++d) {
            if (d < dg)
                rows[d] = *(reinterpret_cast<const u32x4*>(
                                y1b + (size_t)idx[d] * VROW) + j);
        }

        // prefetch next tile's idx/deg/y0 under the gather latency
        const int tn = (t + GTB < NTB) ? t + GTB : t;
        int idxn[ND];
        int dgn;
        u32x4 sun;
        {
            int v = tn * 32 + vloc;
            const int vc = v < NV ? v : NV - 1;
            const int4* p = reinterpret_cast<const int4*>(nbrb + (size_t)vc * ND);
            int4 a0 = p[0], a1 = p[1], a2 = p[2];
            idxn[0] = a0.x; idxn[1] = a0.y; idxn[2]  = a0.z; idxn[3]  = a0.w;
            idxn[4] = a1.x; idxn[5] = a1.y; idxn[6]  = a1.z; idxn[7]  = a1.w;
            idxn[8] = a2.x; idxn[9] = a2.y; idxn[10] = a2.z; idxn[11] = a2.w;
            dgn = degb[vc];
            sun = *(reinterpret_cast<const u32x4*>(y0b + (size_t)vc * VROW) + j);
        }

        // accumulate neighbor sum (waits on rows[*] only; prefetch stays in flight)
        const float inv = 1.0f / (float)dg;
        float ns[8];
#pragma unroll
        for (int k = 0; k < 8; ++k) ns[k] = 0.0f;
#pragma unroll
        for (int d = 0; d < ND; ++d) {
            if (d < dg) {
                u32x4 u = rows[d];
                ns[0] += blo(u[0]); ns[1] += bhi(u[0]);
                ns[2] += blo(u[1]); ns[3] += bhi(u[1]);
                ns[4] += blo(u[2]); ns[5] += bhi(u[2]);
                ns[6] += blo(u[3]); ns[7] += bhi(u[3]);
            }
        }

        // combine with self (y0 already has bias), stage to LDS[buf]
        {
            float f[8];
            f[0] = __builtin_fmaf(inv, ns[0], blo(su[0]));
            f[1] = __builtin_fmaf(inv, ns[1], bhi(su[0]));
            f[2] = __builtin_fmaf(inv, ns[2], blo(su[1]));
            f[3] = __builtin_fmaf(inv, ns[3], bhi(su[1]));
            f[4] = __builtin_fmaf(inv, ns[4], blo(su[2]));
            f[5] = __builtin_fmaf(inv, ns[5], bhi(su[2]));
            f[6] = __builtin_fmaf(inv, ns[6], blo(su[3]));
            f[7] = __builtin_fmaf(inv, ns[7], bhi(su[3]));
            f32x4 w0 = {f[0], f[1], f[2], f[3]};
            f32x4 w1 = {f[4], f[5], f[6], f[7]};
            *reinterpret_cast<f32x4*>(&lds[buf][vloc * 68 + j * 8])     = w0;
            *reinterpret_cast<f32x4*>(&lds[buf][vloc * 68 + j * 8 + 4]) = w1;
        }
        __syncthreads();   // LDS[buf] complete (also orders dbuf reuse WAR)

        // coalesced store: per instr 2 o-rows x 32 consecutive v (2x128B)
        {
            const int vl = threadIdx.x & 31;
            const int o8 = threadIdx.x >> 5;   // 0..7
            const int vv = t * 32 + vl;
            if (vv < NV) {
#pragma unroll
                for (int oo = 0; oo < 8; ++oo) {
                    const int o = oo * 8 + o8;
                    __builtin_nontemporal_store(lds[buf][vl * 68 + o],
                                                outb + (size_t)o * NV + vv);
                }
            }
        }

        // rotate pipeline registers
        buf ^= 1;
        dg = dgn;
        su = sun;
#pragma unroll
        for (int d = 0; d < ND; ++d) idx[d] = idxn[d];
    }
}

// ---- Fallback (workspace too small): correct but slow ----
__global__ __launch_bounds__(64) void fallback_kernel(const float* __restrict__ x,
                                                      const int* __restrict__ nbr,
                                                      const int* __restrict__ deg,
                                                      const float* __restrict__ W,
                                                      const float* __restrict__ bias,
                                                      float* __restrict__ out) {
    const int bvi = blockIdx.x;
    const int b = bvi / NV, v = bvi % NV;
    const int o = threadIdx.x;
    const int degv = deg[bvi];
    const float inv = 1.0f / (float)degv;
    float acc = bias[o];
    for (int c = 0; c < NC; ++c) {
        const float* xc = x + ((size_t)b * NC + c) * NV;
        float m = 0.0f;
        for (int d = 0; d < degv; ++d) m += xc[nbr[(size_t)bvi * ND + d]];
        acc += W[o * (NC * 2) + c * 2] * xc[v] + W[o * (NC * 2) + c * 2 + 1] * (m * inv);
    }
    out[((size_t)b * NO + o) * NV + v] = acc;
}

extern "C" void kernel_launch(void* const* d_in, const int* in_sizes, int n_in,
                              void* d_out, int out_size, void* d_ws, size_t ws_size,
                              hipStream_t stream) {
    const float* x    = (const float*)d_in[0];
    const int*   nbr  = (const int*)d_in[1];
    const int*   deg  = (const int*)d_in[2];
    const float* W    = (const float*)d_in[3];
    const float* bias = (const float*)d_in[4];
    float* out = (float*)d_out;

    const size_t wcb_dw = 4096;                     // 128x64 bf16 as dwords
    const size_t plane  = (size_t)NB * NV * VROW;   // dwords per bf16 plane
    const size_t need = (wcb_dw + 2 * plane) * 4;   // Wcb + y0 + y1
    if (ws_size >= need) {
        uint32_t* Wcb = (uint32_t*)d_ws;
        uint32_t* y0  = Wcb + wcb_dw;
        uint32_t* y1  = y0 + plane;
        wt_kernel<<<dim3(16), 256, 0, stream>>>(W, Wcb);
        ygemm3<<<dim3(NB * ATL), 256, 0, stream>>>(x, Wcb, bias, y0, y1);
        gather3<<<dim3(NB * GTB), 256, 0, stream>>>(nbr, deg, y0, y1, out);
    } else {
        fallback_kernel<<<dim3(NB * NV), 64, 0, stream>>>(x, nbr, deg, W, bias, out);
    }
}

// Round 5
// 184.010 us; speedup vs baseline: 1.0226x; 1.0226x over previous
//
#include <hip/hip_runtime.h>
#include <stdint.h>

// MeshConvPoint: B=8, C=64, V=25000, D=12, O=64
// out[b,o,v] = bias[o] + sum_c W0[o,c]*x[b,c,v] + (1/deg)*sum_{d<deg} y1[b,o,nbr[b,v,d]]
//
// R12: fix the GEMM staging join + occupancy. Evidence across R8-R11: any
// kernel doing the x-transpose via register pack-join (buffer 8 packs, one
// ds_write_b128 joining 16 loads at vmcnt(0)) runs 46-54us at ~13-17 waves/CU;
// R9's split xt_kernel (1 load -> 1 dependent LDS write, vmcnt ladder, full
// occ) was fast. ygemm5 keeps the fusion but stages per-pair (load c, load
// c+1, pack, ds_write_b32 -- drains in steps of 2) and goes register-lean:
// 512 thr / 64 v / 8 waves, wave = (plane, vsub), acc[4] = 16 AGPR only,
// __launch_bounds__(512,6) -> ~24 waves/CU (~2x ygemm3). One barrier.
// wt / gather3 byte-identical to R11 (isolation). XCD pin: blockIdx.x&7 = b.

#define NB 8
#define NC 64
#define NV 25000
#define ND 12
#define NO 64
#define VROW 32        // y0/y1 row stride in dwords (64 bf16 = 128 B)
#define ATL 391        // ceil(25000/64) tiles for ygemm5 (64 v / block)
#define NTB 782        // ceil(25000/32) 32-v tiles per batch for gather
#define GTB 256        // gather blocks per batch (persistent)

typedef uint32_t u32x4 __attribute__((ext_vector_type(4)));
typedef uint32_t u32x2 __attribute__((ext_vector_type(2)));
typedef __bf16  bf16x8 __attribute__((ext_vector_type(8)));
typedef float   f32x4  __attribute__((ext_vector_type(4)));

__device__ inline uint32_t bf16pack(float a, float b) {
    uint32_t ua = __float_as_uint(a), ub = __float_as_uint(b);
    ua = (ua + 0x7fffu + ((ua >> 16) & 1u)) >> 16;
    ub = (ub + 0x7fffu + ((ub >> 16) & 1u)) >> 16;
    return ua | (ub << 16);
}
__device__ inline float blo(uint32_t u) { return __uint_as_float(u << 16); }
__device__ inline float bhi(uint32_t u) { return __uint_as_float(u & 0xffff0000u); }

// ---- K0: W[o][c][k] -> Wcb[m][c-pair] bf16, m = k*64 + o ----
__global__ __launch_bounds__(256) void wt_kernel(const float* __restrict__ W,
                                                 uint32_t* __restrict__ Wcb) {
    int i = blockIdx.x * 256 + threadIdx.x;  // i in [0, 4096)
    int m = i >> 5;             // 0..127
    int c = (i & 31) * 2;       // 0..62 even
    int k = m >> 6;             // plane
    int o = m & 63;
    float s0 = W[o * (NC * 2) + c * 2 + k];
    float s1 = W[o * (NC * 2) + (c + 1) * 2 + k];
    Wcb[i] = bf16pack(s0, s1);
}

// ---- K1: x[b][c][v] -> y0 (plane0+bias) and y1 (plane1), bf16 rows ----
// 512 thr / 64 v / 8 waves. Staging: wave w owns c-pairs p = w*4+pp; per
// pair: 2 coalesced 256B loads (lane = v), pack, ds_write_b32 (drain step 2,
// no deep join). LDS rows [v][c-pair] stride 36 dw. Compute: wave w ->
// plane pl = w>>2, v-sub = w&3 (16 v): 2 ds_read_b128 frags, 8 Wcb loads
// (L1-resident), 8 MFMAs, acc[4] = 16 AGPR.
__global__ __launch_bounds__(512, 6) void ygemm5(const float* __restrict__ x,
                                                 const uint32_t* __restrict__ Wcb,
                                                 const float* __restrict__ bias,
                                                 uint32_t* __restrict__ y0,
                                                 uint32_t* __restrict__ y1) {
    __shared__ uint32_t lb[64 * 36];
    const int b = blockIdx.x & 7;      // XCD pin
    const int tile = blockIdx.x >> 3;
    const int vbase = tile * 64;
    const int lane = threadIdx.x & 63, wave = threadIdx.x >> 6;  // wave 0..7
    const float* xb = x + (size_t)b * NC * NV;

    // staging: per pair, load -> pack -> write immediately (shallow drains)
    {
        int vg = vbase + lane;
        if (vg >= NV) vg = NV - 1;
#pragma unroll
        for (int pp = 0; pp < 4; ++pp) {
            const int p = wave * 4 + pp;   // c-pair 0..31
            const int c = p * 2;
            float s0 = __builtin_nontemporal_load(xb + (size_t)c * NV + vg);
            float s1 = __builtin_nontemporal_load(xb + (size_t)(c + 1) * NV + vg);
            lb[lane * 36 + p] = bf16pack(s0, s1);
        }
    }
    __syncthreads();

    const int l15 = lane & 15, lq = lane >> 4;
    const int pl  = wave >> 2;         // plane 0/1 (wave-uniform)
    const int sub = wave & 3;          // v-subtile 0..3

    union BF { u32x4 q; bf16x8 v; } bfr[2];
#pragma unroll
    for (int kt = 0; kt < 2; ++kt)
        bfr[kt].q = *reinterpret_cast<const u32x4*>(
            &lb[(sub * 16 + l15) * 36 + kt * 16 + lq * 4]);

    f32x4 acc[4];
#pragma unroll
    for (int mt = 0; mt < 4; ++mt) acc[mt] = (f32x4){0.f, 0.f, 0.f, 0.f};

#pragma unroll
    for (int kt = 0; kt < 2; ++kt) {
#pragma unroll
        for (int mt = 0; mt < 4; ++mt) {
            union { u32x4 q; bf16x8 v; } au;
            au.q = *(const u32x4*)(Wcb + (size_t)(pl * 64 + mt * 16 + l15) * 32
                                       + kt * 16 + lq * 4);
            acc[mt] = __builtin_amdgcn_mfma_f32_16x16x32_bf16(au.v, bfr[kt].v,
                                                              acc[mt], 0, 0, 0);
        }
    }

    // lane holds D[o = mt*16 + lq*4 + r][v = l15]; y rows are [v][o-pair]
    const int v = vbase + sub * 16 + l15;
    if (v < NV) {
        if (pl == 0) {
            uint32_t* yr0 = y0 + ((size_t)b * NV + v) * VROW;
#pragma unroll
            for (int mt = 0; mt < 4; ++mt) {
                f32x4 a = acc[mt];
                const float* bp = bias + mt * 16 + lq * 4;
                a[0] += bp[0]; a[1] += bp[1]; a[2] += bp[2]; a[3] += bp[3];
                u32x2 p0 = {bf16pack(a[0], a[1]), bf16pack(a[2], a[3])};
                __builtin_nontemporal_store(p0, (u32x2*)(yr0 + mt * 8 + lq * 2));
            }
        } else {
            uint32_t* yr1 = y1 + ((size_t)b * NV + v) * VROW;
#pragma unroll
            for (int mt = 0; mt < 4; ++mt) {
                f32x4 a = acc[mt];
                u32x2 p1 = {bf16pack(a[0], a[1]), bf16pack(a[2], a[3])};
                *(u32x2*)(yr1 + mt * 8 + lq * 2) = p1;  // hot gather target: L2
            }
        }
    }
}

// ---- K2: persistent pipelined gather: out = y0 + inv * sum(y1[nbr]) ----
// (byte-identical to R11 for attribution)
__global__ __launch_bounds__(256) void gather3(const int* __restrict__ nbr,
                                               const int* __restrict__ deg,
                                               const uint32_t* __restrict__ y0,
                                               const uint32_t* __restrict__ y1,
                                               float* __restrict__ out) {
    __shared__ float lds[2][32 * 68];  // [buf][vloc][o], stride 68

    const int b = blockIdx.x & 7;      // XCD pin (matches producer)
    const int t0 = blockIdx.x >> 3;    // 0..255
    const int lane = threadIdx.x & 63;
    const int wave = threadIdx.x >> 6;
    const int s8 = lane >> 3;
    const int j = lane & 7;
    const int vloc = wave * 8 + s8;    // 0..31

    const int* nbrb = nbr + (size_t)b * NV * ND;
    const int* degb = deg + (size_t)b * NV;
    const uint32_t* y0b = y0 + (size_t)b * NV * VROW;
    const uint32_t* y1b = y1 + (size_t)b * NV * VROW;
    float* outb = out + (size_t)b * NO * NV;

    // prologue: prefetch tile t0's idx/deg/y0
    int idx[ND];
    int dg;
    u32x4 su;
    {
        int v = t0 * 32 + vloc;
        const int vc = v < NV ? v : NV - 1;
        const int4* p = reinterpret_cast<const int4*>(nbrb + (size_t)vc * ND);
        int4 a0 = p[0], a1 = p[1], a2 = p[2];
        idx[0] = a0.x; idx[1] = a0.y; idx[2]  = a0.z; idx[3]  = a0.w;
        idx[4] = a1.x; idx[5] = a1.y; idx[6]  = a1.z; idx[7]  = a1.w;
        idx[8] = a2.x; idx[9] = a2.y; idx[10] = a2.z; idx[11] = a2.w;
        dg = degb[vc];
        su = *(reinterpret_cast<const u32x4*>(y0b + (size_t)vc * VROW) + j);
    }

    int buf = 0;
    for (int t = t0; t < NTB; t += GTB) {
        // issue this tile's 12 masked row gathers (long latency, 12 deep)
        u32x4 rows[ND];
#pragma unroll
        for (int d = 0; d < ND; ++d) {
            if (d < dg)
                rows[d] = *(reinterpret_cast<const u32x4*>(
                                y1b + (size_t)idx[d] * VROW) + j);
        }

        // prefetch next tile's idx/deg/y0 under the gather latency
        const int tn = (t + GTB < NTB) ? t + GTB : t;
        int idxn[ND];
        int dgn;
        u32x4 sun;
        {
            int v = tn * 32 + vloc;
            const int vc = v < NV ? v : NV - 1;
            const int4* p = reinterpret_cast<const int4*>(nbrb + (size_t)vc * ND);
            int4 a0 = p[0], a1 = p[1], a2 = p[2];
            idxn[0] = a0.x; idxn[1] = a0.y; idxn[2]  = a0.z; idxn[3]  = a0.w;
            idxn[4] = a1.x; idxn[5] = a1.y; idxn[6]  = a1.z; idxn[7]  = a1.w;
            idxn[8] = a2.x; idxn[9] = a2.y; idxn[10] = a2.z; idxn[11] = a2.w;
            dgn = degb[vc];
            sun = *(reinterpret_cast<const u32x4*>(y0b + (size_t)vc * VROW) + j);
        }

        // accumulate neighbor sum (waits on rows[*] only; prefetch in flight)
        const float inv = 1.0f / (float)dg;
        float ns[8];
#pragma unroll
        for (int k = 0; k < 8; ++k) ns[k] = 0.0f;
#pragma unroll
        for (int d = 0; d < ND; ++d) {
            if (d < dg) {
                u32x4 u = rows[d];
                ns[0] += blo(u[0]); ns[1] += bhi(u[0]);
                ns[2] += blo(u[1]); ns[3] += bhi(u[1]);
                ns[4] += blo(u[2]); ns[5] += bhi(u[2]);
                ns[6] += blo(u[3]); ns[7] += bhi(u[3]);
            }
        }

        // combine with self (y0 already has bias), stage to LDS[buf]
        {
            float f[8];
            f[0] = __builtin_fmaf(inv, ns[0], blo(su[0]));
            f[1] = __builtin_fmaf(inv, ns[1], bhi(su[0]));
            f[2] = __builtin_fmaf(inv, ns[2], blo(su[1]));
            f[3] = __builtin_fmaf(inv, ns[3], bhi(su[1]));
            f[4] = __builtin_fmaf(inv, ns[4], blo(su[2]));
            f[5] = __builtin_fmaf(inv, ns[5], bhi(su[2]));
            f[6] = __builtin_fmaf(inv, ns[6], blo(su[3]));
            f[7] = __builtin_fmaf(inv, ns[7], bhi(su[3]));
            f32x4 w0 = {f[0], f[1], f[2], f[3]};
            f32x4 w1 = {f[4], f[5], f[6], f[7]};
            *reinterpret_cast<f32x4*>(&lds[buf][vloc * 68 + j * 8])     = w0;
            *reinterpret_cast<f32x4*>(&lds[buf][vloc * 68 + j * 8 + 4]) = w1;
        }
        __syncthreads();   // LDS[buf] complete (also orders dbuf reuse WAR)

        // coalesced store: per instr 2 o-rows x 32 consecutive v (2x128B)
        {
            const int vl = threadIdx.x & 31;
            const int o8 = threadIdx.x >> 5;   // 0..7
            const int vv = t * 32 + vl;
            if (vv < NV) {
#pragma unroll
                for (int oo = 0; oo < 8; ++oo) {
                    const int o = oo * 8 + o8;
                    __builtin_nontemporal_store(lds[buf][vl * 68 + o],
                                                outb + (size_t)o * NV + vv);
                }
            }
        }

        // rotate pipeline registers
        buf ^= 1;
        dg = dgn;
        su = sun;
#pragma unroll
        for (int d = 0; d < ND; ++d) idx[d] = idxn[d];
    }
}

// ---- Fallback (workspace too small): correct but slow ----
__global__ __launch_bounds__(64) void fallback_kernel(const float* __restrict__ x,
                                                      const int* __restrict__ nbr,
                                                      const int* __restrict__ deg,
                                                      const float* __restrict__ W,
                                                      const float* __restrict__ bias,
                                                      float* __restrict__ out) {
    const int bvi = blockIdx.x;
    const int b = bvi / NV, v = bvi % NV;
    const int o = threadIdx.x;
    const int degv = deg[bvi];
    const float inv = 1.0f / (float)degv;
    float acc = bias[o];
    for (int c = 0; c < NC; ++c) {
        const float* xc = x + ((size_t)b * NC + c) * NV;
        float m = 0.0f;
        for (int d = 0; d < degv; ++d) m += xc[nbr[(size_t)bvi * ND + d]];
        acc += W[o * (NC * 2) + c * 2] * xc[v] + W[o * (NC * 2) + c * 2 + 1] * (m * inv);
    }
    out[((size_t)b * NO + o) * NV + v] = acc;
}

extern "C" void kernel_launch(void* const* d_in, const int* in_sizes, int n_in,
                              void* d_out, int out_size, void* d_ws, size_t ws_size,
                              hipStream_t stream) {
    const float* x    = (const float*)d_in[0];
    const int*   nbr  = (const int*)d_in[1];
    const int*   deg  = (const int*)d_in[2];
    const float* W    = (const float*)d_in[3];
    const float* bias = (const float*)d_in[4];
    float* out = (float*)d_out;

    const size_t wcb_dw = 4096;                     // 128x64 bf16 as dwords
    const size_t plane  = (size_t)NB * NV * VROW;   // dwords per bf16 plane
    const size_t need = (wcb_dw + 2 * plane) * 4;   // Wcb + y0 + y1
    if (ws_size >= need) {
        uint32_t* Wcb = (uint32_t*)d_ws;
        uint32_t* y0  = Wcb + wcb_dw;
        uint32_t* y1  = y0 + plane;
        wt_kernel<<<dim3(16), 256, 0, stream>>>(W, Wcb);
        ygemm5<<<dim3(NB * ATL), 512, 0, stream>>>(x, Wcb, bias, y0, y1);
        gather3<<<dim3(NB * GTB), 256, 0, stream>>>(nbr, deg, y0, y1, out);
    } else {
        fallback_kernel<<<dim3(NB * NV), 64, 0, stream>>>(x, nbr, deg, W, bias, out);
    }
}

// Round 6
// 168.607 us; speedup vs baseline: 1.1160x; 1.0914x over previous
//
#include <hip/hip_runtime.h>
#include <stdint.h>

// MeshConvPoint: B=8, C=64, V=25000, D=12, O=64
// out[b,o,v] = bias[o] + sum_c W0[o,c]*x[b,c,v] + (1/deg)*sum_{d<deg} y1[b,o,nbr[b,v,d]]
//
// R13: fix the y write path. Evidence: ygemm dur tracks WRITE_SIZE (~1.3
// TB/s write rate) across R7-R12 while the harness fill proves 6.4 TB/s for
// full-line stores; our u32x2 D-stores scatter 32B partials over 16 lines
// (+nt on y0 streams partials out before L2 merge -> 1.3x amplification).
// ygemm6: 128-v tile, float2 x-loads, XOR-swizzled LDS x-tile; D staged to
// LDS (swizzled, 2-4-way banks) then emitted as FLAT 1024B-per-instruction
// contiguous copies (fill-like). yst0 aliases the x-tile: 34.8KB LDS ->
// 4 blocks/CU. Occupancy ruled out as lever (R12: 60% occ, flat dur).
// wt / gather3 byte-identical to R12 (isolation). XCD pin: blockIdx.x&7=b.

#define NB 8
#define NC 64
#define NV 25000
#define ND 12
#define NO 64
#define VROW 32        // y0/y1 row stride in dwords (64 bf16 = 128 B)
#define NGT 196        // ceil(25000/128) tiles for ygemm6 (128 v / block)
#define NTB 782        // ceil(25000/32) 32-v tiles per batch for gather
#define GTB 256        // gather blocks per batch (persistent)

typedef uint32_t u32x4 __attribute__((ext_vector_type(4)));
typedef uint32_t u32x2 __attribute__((ext_vector_type(2)));
typedef __bf16  bf16x8 __attribute__((ext_vector_type(8)));
typedef float   f32x4  __attribute__((ext_vector_type(4)));

__device__ inline uint32_t bf16pack(float a, float b) {
    uint32_t ua = __float_as_uint(a), ub = __float_as_uint(b);
    ua = (ua + 0x7fffu + ((ua >> 16) & 1u)) >> 16;
    ub = (ub + 0x7fffu + ((ub >> 16) & 1u)) >> 16;
    return ua | (ub << 16);
}
__device__ inline float blo(uint32_t u) { return __uint_as_float(u << 16); }
__device__ inline float bhi(uint32_t u) { return __uint_as_float(u & 0xffff0000u); }

// ---- K0: W[o][c][k] -> Wcb[m][c-pair] bf16, m = k*64 + o ----
__global__ __launch_bounds__(256) void wt_kernel(const float* __restrict__ W,
                                                 uint32_t* __restrict__ Wcb) {
    int i = blockIdx.x * 256 + threadIdx.x;  // i in [0, 4096)
    int m = i >> 5;             // 0..127
    int c = (i & 31) * 2;       // 0..62 even
    int k = m >> 6;             // plane
    int o = m & 63;
    float s0 = W[o * (NC * 2) + c * 2 + k];
    float s1 = W[o * (NC * 2) + (c + 1) * 2 + k];
    Wcb[i] = bf16pack(s0, s1);
}

// ---- K1: x[b][c][v] -> y0 (plane0+bias) and y1 (plane1), bf16 rows ----
// 512 thr / 128 v / 8 waves. Stage: wave w owns c-pairs w*4..w*4+3; lane
// loads float2 (2 v) per channel -> pack -> 2x ds_write_b32 into rows
// [v][c-pair] stride 36 dw, dword index XOR-swizzled by ((v>>2)&7)<<2 so
// the 128-row column writes spread banks. Compute: wave = (plane=w>>2,
// vsub32=w&3): 2 subtiles x 2 kt x 4 mt = 16 MFMAs, acc[2][4]=32 AGPR.
// Epilogue: D staged to LDS (swizzled), then FLAT contiguous copy:
// per instruction 64 lanes x 16 B = 1024 B linear (fill-like full lines).
__global__ __launch_bounds__(512, 4) void ygemm6(const float* __restrict__ x,
                                                 const uint32_t* __restrict__ Wcb,
                                                 const float* __restrict__ bias,
                                                 uint32_t* __restrict__ y0,
                                                 uint32_t* __restrict__ y1) {
    __shared__ uint32_t lb[4608 + 4096];   // x-tile [128][36] ; +4096 = yst1
    uint32_t* yst0 = lb;                   // aliases x-tile after bar2
    uint32_t* yst1 = lb + 4608;

    const int b = blockIdx.x & 7;      // XCD pin
    const int tile = blockIdx.x >> 3;
    const int vbase = tile * 128;
    const int t = threadIdx.x;
    const int lane = t & 63, wave = t >> 6;
    const float* xb = x + (size_t)b * NC * NV;

    // ---- stage x ----
    {
        int vg = vbase + lane * 2;
        if (vg > NV - 2) vg = NV - 2;      // clamp keeps float2 in bounds
        const int key = ((lane >> 1) & 7) << 2;  // == ((vl>>2)&7)<<2, vl=2*lane(+1)
#pragma unroll
        for (int pp = 0; pp < 4; ++pp) {
            const int p = wave * 4 + pp;   // c-pair 0..31
            const int c = p * 2;
            u32x2 qa = __builtin_nontemporal_load(
                reinterpret_cast<const u32x2*>(xb + (size_t)c * NV + vg));
            u32x2 qb = __builtin_nontemporal_load(
                reinterpret_cast<const u32x2*>(xb + (size_t)(c + 1) * NV + vg));
            const int pc = p ^ key;
            lb[(lane * 2)     * 36 + pc] =
                bf16pack(__uint_as_float(qa[0]), __uint_as_float(qb[0]));
            lb[(lane * 2 + 1) * 36 + pc] =
                bf16pack(__uint_as_float(qa[1]), __uint_as_float(qb[1]));
        }
    }
    __syncthreads();

    // ---- B frags (swizzled read) ----
    const int l15 = lane & 15, lq = lane >> 4;
    const int pl = wave >> 2, sub = wave & 3;

    union BF { u32x4 q; bf16x8 v; } bfr[2][2];   // [sub16][kt]
#pragma unroll
    for (int s = 0; s < 2; ++s) {
        const int vl = sub * 32 + s * 16 + l15;
        const int key = ((vl >> 2) & 7) << 2;
#pragma unroll
        for (int kt = 0; kt < 2; ++kt)
            bfr[s][kt].q = *reinterpret_cast<const u32x4*>(
                &lb[vl * 36 + ((kt * 16 + lq * 4) ^ key)]);
    }
    __syncthreads();   // all frag reads done -> lb reusable as yst0

    f32x4 acc[2][4];
#pragma unroll
    for (int s = 0; s < 2; ++s)
#pragma unroll
        for (int mt = 0; mt < 4; ++mt) acc[s][mt] = (f32x4){0.f, 0.f, 0.f, 0.f};

#pragma unroll
    for (int kt = 0; kt < 2; ++kt) {
#pragma unroll
        for (int mt = 0; mt < 4; ++mt) {
            union { u32x4 q; bf16x8 v; } au;
            au.q = *(const u32x4*)(Wcb + (size_t)(pl * 64 + mt * 16 + l15) * 32
                                       + kt * 16 + lq * 4);
#pragma unroll
            for (int s = 0; s < 2; ++s)
                acc[s][mt] = __builtin_amdgcn_mfma_f32_16x16x32_bf16(au.v, bfr[s][kt].v,
                                                                     acc[s][mt], 0, 0, 0);
        }
    }

    // ---- stage D to LDS (bf16, swizzled; bias on plane 0) ----
    uint32_t* yst = pl ? yst1 : yst0;
#pragma unroll
    for (int s = 0; s < 2; ++s) {
        const int vrow = sub * 32 + s * 16 + l15;
        const int key = (vrow & 7) << 2;
#pragma unroll
        for (int mt = 0; mt < 4; ++mt) {
            f32x4 a = acc[s][mt];
            if (pl == 0) {
                const float* bp = bias + mt * 16 + lq * 4;
                a[0] += bp[0]; a[1] += bp[1]; a[2] += bp[2]; a[3] += bp[3];
            }
            u32x2 pk = {bf16pack(a[0], a[1]), bf16pack(a[2], a[3])};
            *reinterpret_cast<u32x2*>(&yst[vrow * 32 + ((mt * 8 + lq * 2) ^ key)]) = pk;
        }
    }
    __syncthreads();

    // ---- flat full-line copy: per instr 64 lanes x 16 B = 1024 B linear ----
    {
        uint32_t* y0g = y0 + ((size_t)b * NV + vbase) * VROW;
        uint32_t* y1g = y1 + ((size_t)b * NV + vbase) * VROW;
#pragma unroll
        for (int h = 0; h < 2; ++h) {
            const int ck = t + h * 512;        // 4-dw chunk id, 0..1023
            const int r = ck >> 3;             // local row (v)
            if (vbase + r < NV) {
                const int off = ((ck & 7) * 4) ^ ((r & 7) << 2);
                u32x4 q0 = *reinterpret_cast<const u32x4*>(&yst0[r * 32 + off]);
                __builtin_nontemporal_store(q0, reinterpret_cast<u32x4*>(y0g + ck * 4));
                u32x4 q1 = *reinterpret_cast<const u32x4*>(&yst1[r * 32 + off]);
                *reinterpret_cast<u32x4*>(y1g + ck * 4) = q1;   // hot gather target: L2
            }
        }
    }
}

// ---- K2: persistent pipelined gather: out = y0 + inv * sum(y1[nbr]) ----
// (byte-identical to R11/R12 for attribution)
__global__ __launch_bounds__(256) void gather3(const int* __restrict__ nbr,
                                               const int* __restrict__ deg,
                                               const uint32_t* __restrict__ y0,
                                               const uint32_t* __restrict__ y1,
                                               float* __restrict__ out) {
    __shared__ float lds[2][32 * 68];  // [buf][vloc][o], stride 68

    const int b = blockIdx.x & 7;      // XCD pin (matches producer)
    const int t0 = blockIdx.x >> 3;    // 0..255
    const int lane = threadIdx.x & 63;
    const int wave = threadIdx.x >> 6;
    const int s8 = lane >> 3;
    const int j = lane & 7;
    const int vloc = wave * 8 + s8;    // 0..31

    const int* nbrb = nbr + (size_t)b * NV * ND;
    const int* degb = deg + (size_t)b * NV;
    const uint32_t* y0b = y0 + (size_t)b * NV * VROW;
    const uint32_t* y1b = y1 + (size_t)b * NV * VROW;
    float* outb = out + (size_t)b * NO * NV;

    // prologue: prefetch tile t0's idx/deg/y0
    int idx[ND];
    int dg;
    u32x4 su;
    {
        int v = t0 * 32 + vloc;
        const int vc = v < NV ? v : NV - 1;
        const int4* p = reinterpret_cast<const int4*>(nbrb + (size_t)vc * ND);
        int4 a0 = p[0], a1 = p[1], a2 = p[2];
        idx[0] = a0.x; idx[1] = a0.y; idx[2]  = a0.z; idx[3]  = a0.w;
        idx[4] = a1.x; idx[5] = a1.y; idx[6]  = a1.z; idx[7]  = a1.w;
        idx[8] = a2.x; idx[9] = a2.y; idx[10] = a2.z; idx[11] = a2.w;
        dg = degb[vc];
        su = *(reinterpret_cast<const u32x4*>(y0b + (size_t)vc * VROW) + j);
    }

    int buf = 0;
    for (int t = t0; t < NTB; t += GTB) {
        // issue this tile's 12 masked row gathers (long latency, 12 deep)
        u32x4 rows[ND];
#pragma unroll
        for (int d = 0; d < ND; ++d) {
            if (d < dg)
                rows[d] = *(reinterpret_cast<const u32x4*>(
                                y1b + (size_t)idx[d] * VROW) + j);
        }

        // prefetch next tile's idx/deg/y0 under the gather latency
        const int tn = (t + GTB < NTB) ? t + GTB : t;
        int idxn[ND];
        int dgn;
        u32x4 sun;
        {
            int v = tn * 32 + vloc;
            const int vc = v < NV ? v : NV - 1;
            const int4* p = reinterpret_cast<const int4*>(nbrb + (size_t)vc * ND);
            int4 a0 = p[0], a1 = p[1], a2 = p[2];
            idxn[0] = a0.x; idxn[1] = a0.y; idxn[2]  = a0.z; idxn[3]  = a0.w;
            idxn[4] = a1.x; idxn[5] = a1.y; idxn[6]  = a1.z; idxn[7]  = a1.w;
            idxn[8] = a2.x; idxn[9] = a2.y; idxn[10] = a2.z; idxn[11] = a2.w;
            dgn = degb[vc];
            sun = *(reinterpret_cast<const u32x4*>(y0b + (size_t)vc * VROW) + j);
        }

        // accumulate neighbor sum (waits on rows[*] only; prefetch in flight)
        const float inv = 1.0f / (float)dg;
        float ns[8];
#pragma unroll
        for (int k = 0; k < 8; ++k) ns[k] = 0.0f;
#pragma unroll
        for (int d = 0; d < ND; ++d) {
            if (d < dg) {
                u32x4 u = rows[d];
                ns[0] += blo(u[0]); ns[1] += bhi(u[0]);
                ns[2] += blo(u[1]); ns[3] += bhi(u[1]);
                ns[4] += blo(u[2]); ns[5] += bhi(u[2]);
                ns[6] += blo(u[3]); ns[7] += bhi(u[3]);
            }
        }

        // combine with self (y0 already has bias), stage to LDS[buf]
        {
            float f[8];
            f[0] = __builtin_fmaf(inv, ns[0], blo(su[0]));
            f[1] = __builtin_fmaf(inv, ns[1], bhi(su[0]));
            f[2] = __builtin_fmaf(inv, ns[2], blo(su[1]));
            f[3] = __builtin_fmaf(inv, ns[3], bhi(su[1]));
            f[4] = __builtin_fmaf(inv, ns[4], blo(su[2]));
            f[5] = __builtin_fmaf(inv, ns[5], bhi(su[2]));
            f[6] = __builtin_fmaf(inv, ns[6], blo(su[3]));
            f[7] = __builtin_fmaf(inv, ns[7], bhi(su[3]));
            f32x4 w0 = {f[0], f[1], f[2], f[3]};
            f32x4 w1 = {f[4], f[5], f[6], f[7]};
            *reinterpret_cast<f32x4*>(&lds[buf][vloc * 68 + j * 8])     = w0;
            *reinterpret_cast<f32x4*>(&lds[buf][vloc * 68 + j * 8 + 4]) = w1;
        }
        __syncthreads();   // LDS[buf] complete (also orders dbuf reuse WAR)

        // coalesced store: per instr 2 o-rows x 32 consecutive v (2x128B)
        {
            const int vl = threadIdx.x & 31;
            const int o8 = threadIdx.x >> 5;   // 0..7
            const int vv = t * 32 + vl;
            if (vv < NV) {
#pragma unroll
                for (int oo = 0; oo < 8; ++oo) {
                    const int o = oo * 8 + o8;
                    __builtin_nontemporal_store(lds[buf][vl * 68 + o],
                                                outb + (size_t)o * NV + vv);
                }
            }
        }

        // rotate pipeline registers
        buf ^= 1;
        dg = dgn;
        su = sun;
#pragma unroll
        for (int d = 0; d < ND; ++d) idx[d] = idxn[d];
    }
}

// ---- Fallback (workspace too small): correct but slow ----
__global__ __launch_bounds__(64) void fallback_kernel(const float* __restrict__ x,
                                                      const int* __restrict__ nbr,
                                                      const int* __restrict__ deg,
                                                      const float* __restrict__ W,
                                                      const float* __restrict__ bias,
                                                      float* __restrict__ out) {
    const int bvi = blockIdx.x;
    const int b = bvi / NV, v = bvi % NV;
    const int o = threadIdx.x;
    const int degv = deg[bvi];
    const float inv = 1.0f / (float)degv;
    float acc = bias[o];
    for (int c = 0; c < NC; ++c) {
        const float* xc = x + ((size_t)b * NC + c) * NV;
        float m = 0.0f;
        for (int d = 0; d < degv; ++d) m += xc[nbr[(size_t)bvi * ND + d]];
        acc += W[o * (NC * 2) + c * 2] * xc[v] + W[o * (NC * 2) + c * 2 + 1] * (m * inv);
    }
    out[((size_t)b * NO + o) * NV + v] = acc;
}

extern "C" void kernel_launch(void* const* d_in, const int* in_sizes, int n_in,
                              void* d_out, int out_size, void* d_ws, size_t ws_size,
                              hipStream_t stream) {
    const float* x    = (const float*)d_in[0];
    const int*   nbr  = (const int*)d_in[1];
    const int*   deg  = (const int*)d_in[2];
    const float* W    = (const float*)d_in[3];
    const float* bias = (const float*)d_in[4];
    float* out = (float*)d_out;

    const size_t wcb_dw = 4096;                     // 128x64 bf16 as dwords
    const size_t plane  = (size_t)NB * NV * VROW;   // dwords per bf16 plane
    const size_t need = (wcb_dw + 2 * plane) * 4;   // Wcb + y0 + y1
    if (ws_size >= need) {
        uint32_t* Wcb = (uint32_t*)d_ws;
        uint32_t* y0  = Wcb + wcb_dw;
        uint32_t* y1  = y0 + plane;
        wt_kernel<<<dim3(16), 256, 0, stream>>>(W, Wcb);
        ygemm6<<<dim3(NB * NGT), 512, 0, stream>>>(x, Wcb, bias, y0, y1);
        gather3<<<dim3(NB * GTB), 256, 0, stream>>>(nbr, deg, y0, y1, out);
    } else {
        fallback_kernel<<<dim3(NB * NV), 64, 0, stream>>>(x, nbr, deg, W, bias, out);
    }
}